// Round 6
// baseline (513.043 us; speedup 1.0000x reference)
//
#include <hip/hip_runtime.h>

// SoftAttention: B=4, Q=64, S=1024, H=512, fp32.
// out = [context (B*Q*H)] ++ [weights (B*Q*S)]
// ws layout: Eq [256*512]f32 @0; Ek [4096*512]f32 @+512KB;
//            Bhi/Blo (bf16 hi/lo of W, granule-major) @+8.5MB (1MB each);
//            Xhi/Xlo (bf16 hi/lo of X, granule-major) @+10.5MB (4.25MB each);
//            sraw (raw scores) @+19MB (1MB).
//
// R6: MEASUREMENT ROUND (R5 retry; R5 failed on container infra, not kernel).
// Kernels are byte-identical to R4 except each body is wrapped in an
// idempotent rep-loop (convert x20, proj x10, score x4, ctx x10) to push
// every kernel past the ~45us fill cutoff so the top-5 table reveals
// per-kernel durations and counters. Base time = shown / rep. Math unchanged.

constexpr int kB = 4;
constexpr int kQ = 64;
constexpr int kS = 1024;
constexpr int kH = 512;

typedef short bf16x8 __attribute__((ext_vector_type(8)));
typedef float f32x4 __attribute__((ext_vector_type(4)));

__device__ __forceinline__ unsigned bf16rtn_bits(float x) {
  unsigned u = __float_as_uint(x);
  u += 0x7FFFu + ((u >> 16) & 1u);
  return u;  // hi bf16 = u>>16; its f32 bits = u & 0xFFFF0000
}

// ---------------------------------------------------------------------------
// Fused converter (rep x20 for measurement).
// ---------------------------------------------------------------------------
__global__ __launch_bounds__(256) void convert_all(
    const float* __restrict__ Wk, const float* __restrict__ Wq,
    const float* __restrict__ key_, const float* __restrict__ query,
    unsigned short* __restrict__ Bhi, unsigned short* __restrict__ Blo,
    unsigned short* __restrict__ Xhi, unsigned short* __restrict__ Xlo) {
  __shared__ __align__(16) unsigned short LHi[128 * 40];
  __shared__ __align__(16) unsigned short LLo[128 * 40];
  const int bid = blockIdx.x;
  const int t = threadIdx.x;
#pragma unroll 1
  for (int rep = 0; rep < 20; ++rep) {
    asm volatile("" ::: "memory");
    if (bid < 256) {
      const int gid = bid * 256 + t;
      const int c = gid & 63;
      const int g = (gid >> 6) & 3;
      const int kt = (gid >> 8) & 15;
      const int ct = (gid >> 12) & 7;
      const int mat = gid >> 15;
      const float* W = mat ? Wq : Wk;
      const float* src = W + (size_t)(kt * 32 + g * 8) * kH + ct * 64 + c;
      bf16x8 hv, lv;
#pragma unroll
      for (int j = 0; j < 8; j++) {
        float x = src[(size_t)j * kH];
        unsigned u = bf16rtn_bits(x);
        float hf = __uint_as_float(u & 0xFFFF0000u);
        unsigned v = bf16rtn_bits(x - hf);
        hv[j] = (short)(u >> 16);
        lv[j] = (short)(v >> 16);
      }
      *(bf16x8*)(Bhi + (size_t)gid * 8) = hv;
      *(bf16x8*)(Blo + (size_t)gid * 8) = lv;
    } else {
      const int xb = bid - 256;
      const int kt = xb & 15;
      const int rt = xb >> 4;  // 0..33
      const float* X = (rt < 32) ? (key_ + (size_t)rt * 128 * kH)
                                 : (query + (size_t)(rt - 32) * 128 * kH);
      const int r = t >> 1, c0 = (t & 1) * 16;
      const float* src = X + (size_t)r * kH + kt * 32 + c0;
      bf16x8 hv0, hv1, lv0, lv1;
#pragma unroll
      for (int i = 0; i < 16; i++) {
        float x = src[i];
        unsigned u = bf16rtn_bits(x);
        float hf = __uint_as_float(u & 0xFFFF0000u);
        unsigned v = bf16rtn_bits(x - hf);
        if (i < 8) { hv0[i] = (short)(u >> 16); lv0[i] = (short)(v >> 16); }
        else       { hv1[i - 8] = (short)(u >> 16); lv1[i - 8] = (short)(v >> 16); }
      }
      __syncthreads();  // protect LDS across reps (before overwrite)
      *(bf16x8*)&LHi[r * 40 + c0] = hv0;
      *(bf16x8*)&LHi[r * 40 + c0 + 8] = hv1;
      *(bf16x8*)&LLo[r * 40 + c0] = lv0;
      *(bf16x8*)&LLo[r * 40 + c0 + 8] = lv1;
      __syncthreads();
      const size_t obase = (size_t)(rt * 16 + kt) * 512 * 8;
#pragma unroll
      for (int p = 0; p < 2; p++) {
        const int s = t + p * 256;
        const int rr = s & 127, g = s >> 7;
        *(uint4*)(Xhi + obase + (size_t)s * 8) = *(const uint4*)&LHi[rr * 40 + g * 8];
        *(uint4*)(Xlo + obase + (size_t)s * 8) = *(const uint4*)&LLo[rr * 40 + g * 8];
      }
    }
  }
}

// ---------------------------------------------------------------------------
// Projection via MFMA (rep x10 for measurement).
// ---------------------------------------------------------------------------
__global__ __launch_bounds__(512) void proj_mfma(
    const unsigned short* __restrict__ Xhi, const unsigned short* __restrict__ Xlo,
    const unsigned short* __restrict__ Bhi, const unsigned short* __restrict__ Blo,
    const float* __restrict__ bk, const float* __restrict__ bq,
    float* __restrict__ Ek, float* __restrict__ Eq) {
  __shared__ __align__(16) unsigned short AhiL[2][4096];
  __shared__ __align__(16) unsigned short AloL[2][4096];
  __shared__ __align__(16) unsigned short BhiL[2][2048];
  __shared__ __align__(16) unsigned short BloL[2][2048];

  const int ct = blockIdx.x;
  const int rt = blockIdx.y;  // 0..33
  const int mat = (rt >= 32) ? 1 : 0;
  const float* bias = mat ? bq : bk;
  float* Y = mat ? (Eq + (size_t)(rt - 32) * 128 * kH)
                 : (Ek + (size_t)rt * 128 * kH);

  const int t = threadIdx.x;
  const unsigned short* ah_src = Xhi + ((size_t)(rt * 16) * 512 + t) * 8;
  const unsigned short* al_src = Xlo + ((size_t)(rt * 16) * 512 + t) * 8;
  const int bslot = t & 255;
  const unsigned short* b_src =
      ((t < 256) ? Bhi : Blo) + ((size_t)((mat * 8 + ct) * 16) * 256 + bslot) * 8;

  uint4 pah, pal, pb;
  auto gload = [&](int kt2) {
    pah = *(const uint4*)(ah_src + (size_t)kt2 * 512 * 8);
    pal = *(const uint4*)(al_src + (size_t)kt2 * 512 * 8);
    pb = *(const uint4*)(b_src + (size_t)kt2 * 256 * 8);
  };
  auto lwrite = [&](int buf) {
    *(uint4*)&AhiL[buf][t * 8] = pah;
    *(uint4*)&AloL[buf][t * 8] = pal;
    if (t < 256) *(uint4*)&BhiL[buf][bslot * 8] = pb;
    else         *(uint4*)&BloL[buf][bslot * 8] = pb;
  };

  const int l = t & 63, lg = l >> 4, lr = l & 15;
  const int wv = t >> 6, wm = wv & 3, wn = wv >> 2;

  f32x4 acc[2][2];

#pragma unroll 1
  for (int rep = 0; rep < 10; ++rep) {
    asm volatile("" ::: "memory");
#pragma unroll
    for (int m = 0; m < 2; m++)
#pragma unroll
      for (int n = 0; n < 2; n++) acc[m][n] = {0.f, 0.f, 0.f, 0.f};

    gload(0);
    lwrite(0);
    __syncthreads();

    for (int kt2 = 0; kt2 < 16; kt2++) {
      if (kt2 < 15) gload(kt2 + 1);

      const unsigned short* Ah = AhiL[kt2 & 1];
      const unsigned short* Al = AloL[kt2 & 1];
      const unsigned short* Bh = BhiL[kt2 & 1];
      const unsigned short* Bl = BloL[kt2 & 1];
      bf16x8 ah[2], al[2], bh[2], bl[2];
#pragma unroll
      for (int m = 0; m < 2; m++) {
        const int off = (lg * 128 + wm * 32 + m * 16 + lr) * 8;
        ah[m] = *(const bf16x8*)(Ah + off);
        al[m] = *(const bf16x8*)(Al + off);
      }
#pragma unroll
      for (int n = 0; n < 2; n++) {
        const int off = (lg * 64 + wn * 32 + n * 16 + lr) * 8;
        bh[n] = *(const bf16x8*)(Bh + off);
        bl[n] = *(const bf16x8*)(Bl + off);
      }
#pragma unroll
      for (int m = 0; m < 2; m++)
#pragma unroll
        for (int n = 0; n < 2; n++) {
          acc[m][n] = __builtin_amdgcn_mfma_f32_16x16x32_bf16(ah[m], bh[n], acc[m][n], 0, 0, 0);
          acc[m][n] = __builtin_amdgcn_mfma_f32_16x16x32_bf16(al[m], bh[n], acc[m][n], 0, 0, 0);
          acc[m][n] = __builtin_amdgcn_mfma_f32_16x16x32_bf16(ah[m], bl[n], acc[m][n], 0, 0, 0);
        }

      if (kt2 < 15) {
        __syncthreads();
        lwrite((kt2 + 1) & 1);
        __syncthreads();
      }
    }

    const int col0 = ct * 64 + wn * 32 + lr;
    const float b0 = bias[col0];
    const float b1 = bias[col0 + 16];
#pragma unroll
    for (int m = 0; m < 2; m++) {
      const int row0 = wm * 32 + m * 16 + lg * 4;
#pragma unroll
      for (int jj = 0; jj < 4; jj++) {
        float* y = Y + (size_t)(row0 + jj) * kH;
        y[col0]      = __expf(2.f * (acc[m][0][jj] + b0));
        y[col0 + 16] = __expf(2.f * (acc[m][1][jj] + b1));
      }
    }
    __syncthreads();  // protect LDS across reps
  }
}

// ---------------------------------------------------------------------------
// Scores (rep x4 for measurement).
// ---------------------------------------------------------------------------
__global__ __launch_bounds__(256) void score_kernel(
    const float* __restrict__ Eq, const float* __restrict__ Ek,
    const float* __restrict__ we, float* __restrict__ sraw) {
  __shared__ __align__(16) float EkL[2][64 * 64];

  const int qt = blockIdx.x, st = blockIdx.y, b = blockIdx.z;
  const int t = threadIdx.x, lane = t & 63;
  const int wvu = __builtin_amdgcn_readfirstlane(t >> 6);  // uniform wave id
  const int s0 = st * 64;
  const int q0g = b * kQ + qt * 8;
  const int qA = wvu * 2;

  const float4* we4 = (const float4*)we;
  const float4* qa4 = (const float4*)(Eq + (size_t)(q0g + qA) * kH);
  const float4* qb4 = (const float4*)(Eq + (size_t)(q0g + qA + 1) * kH);

  const int er = t >> 4;
  const int ej = t & 15;
  const float* ekg = Ek + (size_t)(b * kS + s0 + er) * kH + ej * 4;
  float4 pk[4];
  auto gload = [&](int c) {
#pragma unroll
    for (int i = 0; i < 4; i++)
      pk[i] = *(const float4*)(ekg + (size_t)(16 * i) * kH + c * 64);
  };
  auto lwrite = [&](int buf) {
#pragma unroll
    for (int i = 0; i < 4; i++) {
      const int row = er + 16 * i;
      *(float4*)(&EkL[buf][row * 64 + ((ej ^ (row & 15)) << 2)]) = pk[i];
    }
  };

#pragma unroll 1
  for (int rep = 0; rep < 4; ++rep) {
    asm volatile("" ::: "memory");
    float4 u0 = we4[lane * 2], u1 = we4[lane * 2 + 1];
    float wsum = u0.x + u0.y + u0.z + u0.w + u1.x + u1.y + u1.z + u1.w;
#pragma unroll
    for (int off = 32; off; off >>= 1) wsum += __shfl_xor(wsum, off);

    gload(0);
    lwrite(0);
    __syncthreads();

    float accA = 0.f, accB = 0.f;
    const int sw = lane & 15;

    for (int c = 0; c < 8; c++) {
      if (c < 7) gload(c + 1);
      const float* ekb = &EkL[c & 1][lane * 64];
#pragma unroll 4
      for (int g = 0; g < 16; g++) {
        float4 ek = *(const float4*)(ekb + ((g ^ sw) << 2));
        float4 w = we4[c * 16 + g];
        float4 qa = qa4[c * 16 + g];
        float4 qb = qb4[c * 16 + g];
        {
          float a1 = fmaf(qa.x, ek.x, 1.f), b1 = fmaf(qa.y, ek.y, 1.f);
          float n1 = fmaf(w.y, a1, w.x * b1);
          accA = fmaf(n1, __builtin_amdgcn_rcpf(a1 * b1), accA);
          float a2 = fmaf(qa.z, ek.z, 1.f), b2 = fmaf(qa.w, ek.w, 1.f);
          float n2 = fmaf(w.w, a2, w.z * b2);
          accA = fmaf(n2, __builtin_amdgcn_rcpf(a2 * b2), accA);
        }
        {
          float a1 = fmaf(qb.x, ek.x, 1.f), b1 = fmaf(qb.y, ek.y, 1.f);
          float n1 = fmaf(w.y, a1, w.x * b1);
          accB = fmaf(n1, __builtin_amdgcn_rcpf(a1 * b1), accB);
          float a2 = fmaf(qb.z, ek.z, 1.f), b2 = fmaf(qb.w, ek.w, 1.f);
          float n2 = fmaf(w.w, a2, w.z * b2);
          accB = fmaf(n2, __builtin_amdgcn_rcpf(a2 * b2), accB);
        }
      }
      if (c < 7) {
        __syncthreads();
        lwrite((c + 1) & 1);
        __syncthreads();
      }
    }

    sraw[(size_t)(q0g + qA + 0) * kS + s0 + lane] = fmaf(-2.f, accA, wsum);
    sraw[(size_t)(q0g + qA + 1) * kS + s0 + lane] = fmaf(-2.f, accB, wsum);
    __syncthreads();  // protect LDS across reps
  }
}

// ---------------------------------------------------------------------------
// Fused softmax + context + reduce (rep x10 for measurement).
// ---------------------------------------------------------------------------
__global__ __launch_bounds__(256) void ctx_fused(
    const float* __restrict__ sraw, const float* __restrict__ value,
    float* __restrict__ wout, float* __restrict__ ctx) {
  __shared__ __align__(16) float wt[4][1024];
  __shared__ __align__(16) float parts[4][4][128];
  const int bid = blockIdx.x;
  const int qc = bid >> 4, b = (bid >> 2) & 3, hc = bid & 3;
  const int t = threadIdx.x, wv = t >> 6, lane = t & 63;
  const int grow = b * kQ + qc * 4 + wv;

#pragma unroll 1
  for (int rep = 0; rep < 10; ++rep) {
    asm volatile("" ::: "memory");
    // Phase A: softmax of row grow (full row in wave registers).
    const float4* row4 = (const float4*)(sraw + (size_t)grow * kS);
    float4 v[4];
#pragma unroll
    for (int j = 0; j < 4; j++) v[j] = row4[lane + 64 * j];
    float m = -1e30f;
#pragma unroll
    for (int j = 0; j < 4; j++)
      m = fmaxf(m, fmaxf(fmaxf(v[j].x, v[j].y), fmaxf(v[j].z, v[j].w)));
#pragma unroll
    for (int off = 32; off; off >>= 1) m = fmaxf(m, __shfl_xor(m, off));
    float sum = 0.f;
#pragma unroll
    for (int j = 0; j < 4; j++) {
      v[j].x = __expf(v[j].x - m); v[j].y = __expf(v[j].y - m);
      v[j].z = __expf(v[j].z - m); v[j].w = __expf(v[j].w - m);
      sum += v[j].x + v[j].y + v[j].z + v[j].w;
    }
#pragma unroll
    for (int off = 32; off; off >>= 1) sum += __shfl_xor(sum, off);
    const float inv = 1.f / sum;
    float4* wrow = (float4*)&wt[wv][0];
    float4* gw = (float4*)(wout + (size_t)grow * kS);
#pragma unroll
    for (int j = 0; j < 4; j++) {
      v[j].x *= inv; v[j].y *= inv; v[j].z *= inv; v[j].w *= inv;
      wrow[lane + 64 * j] = v[j];
      if (hc == 0) gw[lane + 64 * j] = v[j];
    }
    __syncthreads();

    // Phase B: context accumulate. lane -> float2 of h; wave -> s quarter.
    const float* vbase =
        value + ((size_t)b * kS + wv * 256) * kH + hc * 128 + lane * 2;
    float2 acc[4];
#pragma unroll
    for (int q = 0; q < 4; q++) acc[q] = {0.f, 0.f};
#pragma unroll 2
    for (int s4 = 0; s4 < 64; s4++) {
      float4 wq[4];
#pragma unroll
      for (int q = 0; q < 4; q++)
        wq[q] = *(const float4*)&wt[q][wv * 256 + s4 * 4];
#pragma unroll
      for (int u = 0; u < 4; u++) {
        const float2 vv = *(const float2*)(vbase + (size_t)(s4 * 4 + u) * kH);
        const float w0 = ((const float*)&wq[0])[u];
        const float w1 = ((const float*)&wq[1])[u];
        const float w2 = ((const float*)&wq[2])[u];
        const float w3 = ((const float*)&wq[3])[u];
        acc[0].x = fmaf(w0, vv.x, acc[0].x); acc[0].y = fmaf(w0, vv.y, acc[0].y);
        acc[1].x = fmaf(w1, vv.x, acc[1].x); acc[1].y = fmaf(w1, vv.y, acc[1].y);
        acc[2].x = fmaf(w2, vv.x, acc[2].x); acc[2].y = fmaf(w2, vv.y, acc[2].y);
        acc[3].x = fmaf(w3, vv.x, acc[3].x); acc[3].y = fmaf(w3, vv.y, acc[3].y);
      }
    }
#pragma unroll
    for (int q = 0; q < 4; q++)
      *(float2*)&parts[wv][q][lane * 2] = acc[q];
    __syncthreads();

    // Cross-wave reduce: thread t -> q = t>>6, h-pair = t&63.
    const int q = t >> 6, hp = t & 63;
    float2 r = {0.f, 0.f};
#pragma unroll
    for (int w = 0; w < 4; w++) {
      const float2 p2 = *(const float2*)&parts[w][q][hp * 2];
      r.x += p2.x; r.y += p2.y;
    }
    *(float2*)(ctx + (size_t)(b * kQ + qc * 4 + q) * kH + hc * 128 + hp * 2) = r;
  }
}

extern "C" void kernel_launch(void* const* d_in, const int* in_sizes, int n_in,
                              void* d_out, int out_size, void* d_ws,
                              size_t ws_size, hipStream_t stream) {
  const float* query = (const float*)d_in[0];
  const float* key_  = (const float*)d_in[1];
  const float* value = (const float*)d_in[2];
  const float* Wq    = (const float*)d_in[3];
  const float* bq    = (const float*)d_in[4];
  const float* Wk    = (const float*)d_in[5];
  const float* bk    = (const float*)d_in[6];
  const float* we    = (const float*)d_in[7];
  // be (d_in[8]) cancels in softmax.

  float* ctx  = (float*)d_out;                         // [256*512]
  float* wout = (float*)d_out + (size_t)kB * kQ * kH;  // [256*1024]

  float* Eq = (float*)d_ws;                            // 512 KB
  float* Ek = Eq + (size_t)kB * kQ * kH;               // 8 MB
  unsigned short* Bhi =
      (unsigned short*)((char*)d_ws + (size_t)(kB * kQ * kH + kB * kS * kH) * 4);
  unsigned short* Blo = Bhi + (size_t)2 * 8 * 16 * 256 * 8;  // +1MB
  unsigned short* Xhi = Blo + (size_t)2 * 8 * 16 * 256 * 8;  // +1MB
  unsigned short* Xlo = Xhi + (size_t)34 * 16 * 512 * 8;     // +4.25MB
  float* sraw = (float*)(Xlo + (size_t)34 * 16 * 512 * 8);   // +4.25MB -> 1MB

  convert_all<<<800, 256, 0, stream>>>(Wk, Wq, key_, query, Bhi, Blo, Xhi, Xlo);
  proj_mfma<<<dim3(8, 34), 512, 0, stream>>>(Xhi, Xlo, Bhi, Blo, bk, bq, Ek, Eq);
  score_kernel<<<dim3(8, 16, 4), 256, 0, stream>>>(Eq, Ek, we, sraw);
  ctx_fused<<<256, 256, 0, stream>>>(sraw, value, wout, ctx);
}

// Round 7
// 149.285 us; speedup vs baseline: 3.4367x; 3.4367x over previous
//
#include <hip/hip_runtime.h>

// SoftAttention: B=4, Q=64, S=1024, H=512, fp32.
// out = [context (B*Q*H)] ++ [weights (B*Q*S)]
// ws layout: Eq [256*512]f32 @0; Ek [4096*512]f32 @+512KB;
//            Bhi/Blo (bf16 hi/lo of W, granule-major) @+8.5MB (1MB each);
//            Xhi/Xlo (bf16 hi/lo of X, granule-major) @+10.5MB (4.25MB each);
//            sraw (raw scores) @+19MB (1MB).
//
// R6 measured (rep-instrument): proj=20.1us (MfmaUtil 13.6, Occ 14.4, HBM 27%,
//   FETCH 33.5MB vs 10.5 unique); score~15-30; ctx~2-5; convert~3-6; fill~45.
// R7: proj rebuilt: (a) 64x64 tiles/256thr -> grid 544 (2.1 blk/CU, was 1.06);
//   (b) global_load_lds width-16 staging, 1 barrier/K-step 2-phase prefetch
//   (was reg-staged, 2 barriers + vmcnt(0) drain);
//   (c) XCD swizzle: 8 ct-blocks of an rt share bid%8 -> A-panel L2-local
//   (was round-robined across XCDs, 3x A over-fetch). Rest unchanged.

constexpr int kB = 4;
constexpr int kQ = 64;
constexpr int kS = 1024;
constexpr int kH = 512;

typedef short bf16x8 __attribute__((ext_vector_type(8)));
typedef float f32x4 __attribute__((ext_vector_type(4)));

__device__ __forceinline__ unsigned bf16rtn_bits(float x) {
  unsigned u = __float_as_uint(x);
  u += 0x7FFFu + ((u >> 16) & 1u);
  return u;  // hi bf16 = u>>16; its f32 bits = u & 0xFFFF0000
}

__device__ __forceinline__ void glds16(const void* g, void* l) {
  __builtin_amdgcn_global_load_lds(
      (__attribute__((address_space(1))) void*)(g),
      (__attribute__((address_space(3))) void*)(l), 16, 0, 0);
}

// ---------------------------------------------------------------------------
// Fused converter. Blocks 0..255: W -> Bhi/Blo granule-major
//   (gid = ((mat*8+ct)*16+kt)*256 + g*64+c holds W[kt*32+g*8+j][ct*64+c]).
// Blocks 256..799: X (key_ 4096 rows ++ query 256 rows) -> Xhi/Xlo
//   granule-major per (rt 0..33, kt 0..15): slot g*128+r holds
//   X[rt*128+r][kt*32+g*8+j]; LDS transpose for coalescing.
// ---------------------------------------------------------------------------
__global__ __launch_bounds__(256) void convert_all(
    const float* __restrict__ Wk, const float* __restrict__ Wq,
    const float* __restrict__ key_, const float* __restrict__ query,
    unsigned short* __restrict__ Bhi, unsigned short* __restrict__ Blo,
    unsigned short* __restrict__ Xhi, unsigned short* __restrict__ Xlo) {
  __shared__ __align__(16) unsigned short LHi[128 * 40];
  __shared__ __align__(16) unsigned short LLo[128 * 40];
  const int bid = blockIdx.x;
  const int t = threadIdx.x;
  if (bid < 256) {
    const int gid = bid * 256 + t;
    const int c = gid & 63;
    const int g = (gid >> 6) & 3;
    const int kt = (gid >> 8) & 15;
    const int ct = (gid >> 12) & 7;
    const int mat = gid >> 15;
    const float* W = mat ? Wq : Wk;
    const float* src = W + (size_t)(kt * 32 + g * 8) * kH + ct * 64 + c;
    bf16x8 hv, lv;
#pragma unroll
    for (int j = 0; j < 8; j++) {
      float x = src[(size_t)j * kH];
      unsigned u = bf16rtn_bits(x);
      float hf = __uint_as_float(u & 0xFFFF0000u);
      unsigned v = bf16rtn_bits(x - hf);
      hv[j] = (short)(u >> 16);
      lv[j] = (short)(v >> 16);
    }
    *(bf16x8*)(Bhi + (size_t)gid * 8) = hv;
    *(bf16x8*)(Blo + (size_t)gid * 8) = lv;
    return;
  }
  const int xb = bid - 256;
  const int kt = xb & 15;
  const int rt = xb >> 4;  // 0..33
  const float* X = (rt < 32) ? (key_ + (size_t)rt * 128 * kH)
                             : (query + (size_t)(rt - 32) * 128 * kH);
  const int r = t >> 1, c0 = (t & 1) * 16;
  const float* src = X + (size_t)r * kH + kt * 32 + c0;
  bf16x8 hv0, hv1, lv0, lv1;
#pragma unroll
  for (int i = 0; i < 16; i++) {
    float x = src[i];
    unsigned u = bf16rtn_bits(x);
    float hf = __uint_as_float(u & 0xFFFF0000u);
    unsigned v = bf16rtn_bits(x - hf);
    if (i < 8) { hv0[i] = (short)(u >> 16); lv0[i] = (short)(v >> 16); }
    else       { hv1[i - 8] = (short)(u >> 16); lv1[i - 8] = (short)(v >> 16); }
  }
  *(bf16x8*)&LHi[r * 40 + c0] = hv0;
  *(bf16x8*)&LHi[r * 40 + c0 + 8] = hv1;
  *(bf16x8*)&LLo[r * 40 + c0] = lv0;
  *(bf16x8*)&LLo[r * 40 + c0 + 8] = lv1;
  __syncthreads();
  const size_t obase = (size_t)(rt * 16 + kt) * 512 * 8;
#pragma unroll
  for (int p = 0; p < 2; p++) {
    const int s = t + p * 256;
    const int rr = s & 127, g = s >> 7;
    *(uint4*)(Xhi + obase + (size_t)s * 8) = *(const uint4*)&LHi[rr * 40 + g * 8];
    *(uint4*)(Xlo + obase + (size_t)s * 8) = *(const uint4*)&LLo[rr * 40 + g * 8];
  }
}

// ---------------------------------------------------------------------------
// Projection via MFMA: E = exp(2*(X[4352,512] @ W[512,512] + bias)).
// 64x64 tile, 256 thr = 4 waves (2m x 2n), wave = 2x2 16x16 frags, 12 MFMA
// per K-step (3-product bf16 split). BK=32, double-buffered LDS (32KB),
// global_load_lds width-16 staging (4 instr/thread/step, linear slot=t),
// ONE barrier per K-step (syncthreads' vmcnt drain lands the prefetch).
// grid = (8, 68) = 544 blocks, XCD-swizzled: bid%8 == rt%8 so all 8
// ct-blocks of an rt share one XCD's L2 (A-panel fetched once).
// ---------------------------------------------------------------------------
__global__ __launch_bounds__(256) void proj_mfma(
    const unsigned short* __restrict__ Xhi, const unsigned short* __restrict__ Xlo,
    const unsigned short* __restrict__ Bhi, const unsigned short* __restrict__ Blo,
    const float* __restrict__ bk, const float* __restrict__ bq,
    float* __restrict__ Ek, float* __restrict__ Eq) {
  __shared__ __align__(16) unsigned short AhiL[2][2048];
  __shared__ __align__(16) unsigned short AloL[2][2048];
  __shared__ __align__(16) unsigned short BhiL[2][2048];
  __shared__ __align__(16) unsigned short BloL[2][2048];

  // XCD swizzle: blocks 0..511 cover rt 0..63 with bid%8 == rt%8.
  const int bid = blockIdx.y * 8 + blockIdx.x;
  int ct, rt;
  if (bid < 512) {
    ct = (bid >> 3) & 7;
    rt = (bid & 7) + 8 * (bid >> 6);
  } else {
    const int tb = bid - 512;
    ct = tb >> 2;
    rt = 64 + (tb & 3);
  }

  const int mat = (rt >= 64) ? 1 : 0;
  const float* bias = mat ? bq : bk;
  float* Y = mat ? (Eq + (size_t)(rt - 64) * 64 * kH)
                 : (Ek + (size_t)rt * 64 * kH);

  const int t = threadIdx.x;
  const int rt128 = rt >> 1, hhalf = rt & 1;
  // A: LDS slot t = g*64 + r' (g = t>>6 = wave id); global slot in the
  // (rt128, kt) 512-slot panel = g*128 + hhalf*64 + r'.
  const int ga_slot = ((t >> 6) << 7) + (hhalf << 6) + (t & 63);
  const unsigned short* gah = Xhi + ((size_t)(rt128 * 16) * 512 + ga_slot) * 8;
  const unsigned short* gal = Xlo + ((size_t)(rt128 * 16) * 512 + ga_slot) * 8;
  // B: LDS slot t == global slot t of the (mat,ct,kt) 256-slot panel.
  const unsigned short* gbh = Bhi + (((size_t)(mat * 8 + ct) * 16) * 256 + t) * 8;
  const unsigned short* gbl = Blo + (((size_t)(mat * 8 + ct) * 16) * 256 + t) * 8;

  auto stage = [&](int buf, int kt2) {
    glds16(gah + (size_t)kt2 * 512 * 8, &AhiL[buf][t * 8]);
    glds16(gal + (size_t)kt2 * 512 * 8, &AloL[buf][t * 8]);
    glds16(gbh + (size_t)kt2 * 256 * 8, &BhiL[buf][t * 8]);
    glds16(gbl + (size_t)kt2 * 256 * 8, &BloL[buf][t * 8]);
  };

  const int l = t & 63, lg = l >> 4, lr = l & 15;
  const int wv = t >> 6, wm = wv >> 1, wn = wv & 1;
  const int oa0 = (lg * 64 + wm * 32 + lr) * 8;  // + m*128 for m-frag 1
  const int ob0 = (lg * 64 + wn * 32 + lr) * 8;  // + n*128 for n-frag 1

  f32x4 acc[2][2];
#pragma unroll
  for (int m = 0; m < 2; m++)
#pragma unroll
    for (int n = 0; n < 2; n++) acc[m][n] = {0.f, 0.f, 0.f, 0.f};

  stage(0, 0);
  __syncthreads();

  int buf = 0;
  for (int kt2 = 0; kt2 < 16; kt2++) {
    if (kt2 < 15) stage(buf ^ 1, kt2 + 1);  // prefetch overlaps MFMA below

    const unsigned short* Ah = AhiL[buf];
    const unsigned short* Al = AloL[buf];
    const unsigned short* Bh = BhiL[buf];
    const unsigned short* Bl = BloL[buf];
    bf16x8 ah[2], al[2], bh[2], bl[2];
#pragma unroll
    for (int m = 0; m < 2; m++) {
      ah[m] = *(const bf16x8*)(Ah + oa0 + m * 128);
      al[m] = *(const bf16x8*)(Al + oa0 + m * 128);
    }
#pragma unroll
    for (int n = 0; n < 2; n++) {
      bh[n] = *(const bf16x8*)(Bh + ob0 + n * 128);
      bl[n] = *(const bf16x8*)(Bl + ob0 + n * 128);
    }
#pragma unroll
    for (int m = 0; m < 2; m++)
#pragma unroll
      for (int n = 0; n < 2; n++) {
        acc[m][n] = __builtin_amdgcn_mfma_f32_16x16x32_bf16(ah[m], bh[n], acc[m][n], 0, 0, 0);
        acc[m][n] = __builtin_amdgcn_mfma_f32_16x16x32_bf16(al[m], bh[n], acc[m][n], 0, 0, 0);
        acc[m][n] = __builtin_amdgcn_mfma_f32_16x16x32_bf16(ah[m], bl[n], acc[m][n], 0, 0, 0);
      }

    __syncthreads();  // drains vmcnt (prefetch landed) + syncs LDS readers
    buf ^= 1;
  }

  // Epilogue: E = exp(2*(acc + bias)). C/D: col = lr, row = lg*4 + jj.
  const int col0 = ct * 64 + wn * 32 + lr;
  const float b0 = bias[col0];
  const float b1 = bias[col0 + 16];
#pragma unroll
  for (int m = 0; m < 2; m++) {
    const int row0 = wm * 32 + m * 16 + lg * 4;
#pragma unroll
    for (int jj = 0; jj < 4; jj++) {
      float* y = Y + (size_t)(row0 + jj) * kH;
      y[col0]      = __expf(2.f * (acc[m][0][jj] + b0));
      y[col0 + 16] = __expf(2.f * (acc[m][1][jj] + b1));
    }
  }
}

// ---------------------------------------------------------------------------
// Scores -> sraw[bq][s], lane = s, loop h.  score = wsum - 2*acc where
// acc = sum_h we_h * rcp(1 + Eq*Ek), rcps paired.
// w and Eq rows are wave-uniform -> scalar loads (K$); LDS holds only Ek.
// grid = (8 qt, 16 st, 4 b); 256 thr = 4 waves, wave = 2 q x 64 s.
// ---------------------------------------------------------------------------
__global__ __launch_bounds__(256) void score_kernel(
    const float* __restrict__ Eq, const float* __restrict__ Ek,
    const float* __restrict__ we, float* __restrict__ sraw) {
  __shared__ __align__(16) float EkL[2][64 * 64];

  const int qt = blockIdx.x, st = blockIdx.y, b = blockIdx.z;
  const int t = threadIdx.x, lane = t & 63;
  const int wvu = __builtin_amdgcn_readfirstlane(t >> 6);  // uniform wave id
  const int s0 = st * 64;
  const int q0g = b * kQ + qt * 8;
  const int qA = wvu * 2;

  const float4* we4 = (const float4*)we;
  float4 u0 = we4[lane * 2], u1 = we4[lane * 2 + 1];
  float wsum = u0.x + u0.y + u0.z + u0.w + u1.x + u1.y + u1.z + u1.w;
#pragma unroll
  for (int off = 32; off; off >>= 1) wsum += __shfl_xor(wsum, off);

  const float4* qa4 = (const float4*)(Eq + (size_t)(q0g + qA) * kH);
  const float4* qb4 = (const float4*)(Eq + (size_t)(q0g + qA + 1) * kH);

  const int er = t >> 4;
  const int ej = t & 15;
  const float* ekg = Ek + (size_t)(b * kS + s0 + er) * kH + ej * 4;
  float4 pk[4];
  auto gload = [&](int c) {
#pragma unroll
    for (int i = 0; i < 4; i++)
      pk[i] = *(const float4*)(ekg + (size_t)(16 * i) * kH + c * 64);
  };
  auto lwrite = [&](int buf) {
#pragma unroll
    for (int i = 0; i < 4; i++) {
      const int row = er + 16 * i;
      *(float4*)(&EkL[buf][row * 64 + ((ej ^ (row & 15)) << 2)]) = pk[i];
    }
  };

  gload(0);
  lwrite(0);
  __syncthreads();

  float accA = 0.f, accB = 0.f;
  const int sw = lane & 15;

  for (int c = 0; c < 8; c++) {
    if (c < 7) gload(c + 1);
    const float* ekb = &EkL[c & 1][lane * 64];
#pragma unroll 4
    for (int g = 0; g < 16; g++) {
      float4 ek = *(const float4*)(ekb + ((g ^ sw) << 2));
      float4 w = we4[c * 16 + g];
      float4 qa = qa4[c * 16 + g];
      float4 qb = qb4[c * 16 + g];
      {
        float a1 = fmaf(qa.x, ek.x, 1.f), b1 = fmaf(qa.y, ek.y, 1.f);
        float n1 = fmaf(w.y, a1, w.x * b1);
        accA = fmaf(n1, __builtin_amdgcn_rcpf(a1 * b1), accA);
        float a2 = fmaf(qa.z, ek.z, 1.f), b2 = fmaf(qa.w, ek.w, 1.f);
        float n2 = fmaf(w.w, a2, w.z * b2);
        accA = fmaf(n2, __builtin_amdgcn_rcpf(a2 * b2), accA);
      }
      {
        float a1 = fmaf(qb.x, ek.x, 1.f), b1 = fmaf(qb.y, ek.y, 1.f);
        float n1 = fmaf(w.y, a1, w.x * b1);
        accB = fmaf(n1, __builtin_amdgcn_rcpf(a1 * b1), accB);
        float a2 = fmaf(qb.z, ek.z, 1.f), b2 = fmaf(qb.w, ek.w, 1.f);
        float n2 = fmaf(w.w, a2, w.z * b2);
        accB = fmaf(n2, __builtin_amdgcn_rcpf(a2 * b2), accB);
      }
    }
    if (c < 7) {
      __syncthreads();
      lwrite((c + 1) & 1);
      __syncthreads();
    }
  }

  sraw[(size_t)(q0g + qA + 0) * kS + s0 + lane] = fmaf(-2.f, accA, wsum);
  sraw[(size_t)(q0g + qA + 1) * kS + s0 + lane] = fmaf(-2.f, accB, wsum);
}

// ---------------------------------------------------------------------------
// Fused softmax + context + reduce.
// grid = 256: bid = qc*16 + b*4 + hc. Phase A: wave wv softmaxes row
// (b*64+qc*4+wv) in registers; hc==0 blocks also write wout. Phase B:
// wave wv accumulates its s-quarter for 4 q x 128 h; LDS cross-wave reduce.
// ---------------------------------------------------------------------------
__global__ __launch_bounds__(256) void ctx_fused(
    const float* __restrict__ sraw, const float* __restrict__ value,
    float* __restrict__ wout, float* __restrict__ ctx) {
  __shared__ __align__(16) float wt[4][1024];
  __shared__ __align__(16) float parts[4][4][128];
  const int bid = blockIdx.x;
  const int qc = bid >> 4, b = (bid >> 2) & 3, hc = bid & 3;
  const int t = threadIdx.x, wv = t >> 6, lane = t & 63;
  const int grow = b * kQ + qc * 4 + wv;

  // Phase A: softmax of row grow (full row in wave registers).
  const float4* row4 = (const float4*)(sraw + (size_t)grow * kS);
  float4 v[4];
#pragma unroll
  for (int j = 0; j < 4; j++) v[j] = row4[lane + 64 * j];
  float m = -1e30f;
#pragma unroll
  for (int j = 0; j < 4; j++)
    m = fmaxf(m, fmaxf(fmaxf(v[j].x, v[j].y), fmaxf(v[j].z, v[j].w)));
#pragma unroll
  for (int off = 32; off; off >>= 1) m = fmaxf(m, __shfl_xor(m, off));
  float sum = 0.f;
#pragma unroll
  for (int j = 0; j < 4; j++) {
    v[j].x = __expf(v[j].x - m); v[j].y = __expf(v[j].y - m);
    v[j].z = __expf(v[j].z - m); v[j].w = __expf(v[j].w - m);
    sum += v[j].x + v[j].y + v[j].z + v[j].w;
  }
#pragma unroll
  for (int off = 32; off; off >>= 1) sum += __shfl_xor(sum, off);
  const float inv = 1.f / sum;
  float4* wrow = (float4*)&wt[wv][0];
  float4* gw = (float4*)(wout + (size_t)grow * kS);
#pragma unroll
  for (int j = 0; j < 4; j++) {
    v[j].x *= inv; v[j].y *= inv; v[j].z *= inv; v[j].w *= inv;
    wrow[lane + 64 * j] = v[j];
    if (hc == 0) gw[lane + 64 * j] = v[j];
  }
  __syncthreads();

  // Phase B: context accumulate. lane -> float2 of h; wave -> s quarter.
  const float* vbase =
      value + ((size_t)b * kS + wv * 256) * kH + hc * 128 + lane * 2;
  float2 acc[4];
#pragma unroll
  for (int q = 0; q < 4; q++) acc[q] = {0.f, 0.f};
#pragma unroll 2
  for (int s4 = 0; s4 < 64; s4++) {
    float4 wq[4];
#pragma unroll
    for (int q = 0; q < 4; q++)
      wq[q] = *(const float4*)&wt[q][wv * 256 + s4 * 4];
#pragma unroll
    for (int u = 0; u < 4; u++) {
      const float2 vv = *(const float2*)(vbase + (size_t)(s4 * 4 + u) * kH);
      const float w0 = ((const float*)&wq[0])[u];
      const float w1 = ((const float*)&wq[1])[u];
      const float w2 = ((const float*)&wq[2])[u];
      const float w3 = ((const float*)&wq[3])[u];
      acc[0].x = fmaf(w0, vv.x, acc[0].x); acc[0].y = fmaf(w0, vv.y, acc[0].y);
      acc[1].x = fmaf(w1, vv.x, acc[1].x); acc[1].y = fmaf(w1, vv.y, acc[1].y);
      acc[2].x = fmaf(w2, vv.x, acc[2].x); acc[2].y = fmaf(w2, vv.y, acc[2].y);
      acc[3].x = fmaf(w3, vv.x, acc[3].x); acc[3].y = fmaf(w3, vv.y, acc[3].y);
    }
  }
#pragma unroll
  for (int q = 0; q < 4; q++)
    *(float2*)&parts[wv][q][lane * 2] = acc[q];
  __syncthreads();

  // Cross-wave reduce: thread t -> q = t>>6, h-pair = t&63.
  const int q = t >> 6, hp = t & 63;
  float2 r = {0.f, 0.f};
#pragma unroll
  for (int w = 0; w < 4; w++) {
    const float2 p2 = *(const float2*)&parts[w][q][hp * 2];
    r.x += p2.x; r.y += p2.y;
  }
  *(float2*)(ctx + (size_t)(b * kQ + qc * 4 + q) * kH + hc * 128 + hp * 2) = r;
}

extern "C" void kernel_launch(void* const* d_in, const int* in_sizes, int n_in,
                              void* d_out, int out_size, void* d_ws,
                              size_t ws_size, hipStream_t stream) {
  const float* query = (const float*)d_in[0];
  const float* key_  = (const float*)d_in[1];
  const float* value = (const float*)d_in[2];
  const float* Wq    = (const float*)d_in[3];
  const float* bq    = (const float*)d_in[4];
  const float* Wk    = (const float*)d_in[5];
  const float* bk    = (const float*)d_in[6];
  const float* we    = (const float*)d_in[7];
  // be (d_in[8]) cancels in softmax.

  float* ctx  = (float*)d_out;                         // [256*512]
  float* wout = (float*)d_out + (size_t)kB * kQ * kH;  // [256*1024]

  float* Eq = (float*)d_ws;                            // 512 KB
  float* Ek = Eq + (size_t)kB * kQ * kH;               // 8 MB
  unsigned short* Bhi =
      (unsigned short*)((char*)d_ws + (size_t)(kB * kQ * kH + kB * kS * kH) * 4);
  unsigned short* Blo = Bhi + (size_t)2 * 8 * 16 * 256 * 8;  // +1MB
  unsigned short* Xhi = Blo + (size_t)2 * 8 * 16 * 256 * 8;  // +1MB
  unsigned short* Xlo = Xhi + (size_t)34 * 16 * 512 * 8;     // +4.25MB
  float* sraw = (float*)(Xlo + (size_t)34 * 16 * 512 * 8);   // +4.25MB -> 1MB

  convert_all<<<800, 256, 0, stream>>>(Wk, Wq, key_, query, Bhi, Blo, Xhi, Xlo);
  proj_mfma<<<dim3(8, 68), 256, 0, stream>>>(Xhi, Xlo, Bhi, Blo, bk, bq, Ek, Eq);
  score_kernel<<<dim3(8, 16, 4), 256, 0, stream>>>(Eq, Ek, we, sraw);
  ctx_fused<<<256, 256, 0, stream>>>(sraw, value, wout, ctx);
}